// Round 1
// baseline (14691.290 us; speedup 1.0000x reference)
//
#include <hip/hip_runtime.h>
#include <float.h>

#define BINS 2048
#define DSTN 8
#define STEPF 1e-5f
#define NPART 1024

struct Ws {
  float pmin[NPART];
  float pmax[NPART];
  float min_val, max_val, bin_width, safe_bw;
  int   n_states;
  int   pad[3];
  unsigned int hist[BINS];
  float histf[BINS];
  float norms[BINS];
  int2  states[BINS];
};

// ---------------- Pass 1: block-partial min/max ----------------
__global__ void __launch_bounds__(256) k_minmax(const float* __restrict__ x, long long n,
                                                Ws* __restrict__ ws) {
  long long n4 = n >> 2;
  float vmin = FLT_MAX, vmax = -FLT_MAX;
  const float4* __restrict__ x4 = (const float4*)x;
  long long stride = (long long)gridDim.x * blockDim.x;
  for (long long i = (long long)blockIdx.x * blockDim.x + threadIdx.x; i < n4; i += stride) {
    float4 v = x4[i];
    vmin = fminf(vmin, fminf(fminf(v.x, v.y), fminf(v.z, v.w)));
    vmax = fmaxf(vmax, fmaxf(fmaxf(v.x, v.y), fmaxf(v.z, v.w)));
  }
  // tail (n not multiple of 4)
  for (long long i = (n4 << 2) + (long long)blockIdx.x * blockDim.x + threadIdx.x; i < n; i += stride) {
    float v = x[i];
    vmin = fminf(vmin, v); vmax = fmaxf(vmax, v);
  }
  for (int off = 32; off > 0; off >>= 1) {
    vmin = fminf(vmin, __shfl_down(vmin, off));
    vmax = fmaxf(vmax, __shfl_down(vmax, off));
  }
  __shared__ float smin[4], smax[4];
  int wid = threadIdx.x >> 6;
  if ((threadIdx.x & 63) == 0) { smin[wid] = vmin; smax[wid] = vmax; }
  __syncthreads();
  if (threadIdx.x == 0) {
    float a = smin[0], b = smax[0];
    int nw = (int)(blockDim.x >> 6);
    for (int w = 1; w < nw; ++w) { a = fminf(a, smin[w]); b = fmaxf(b, smax[w]); }
    ws->pmin[blockIdx.x] = a; ws->pmax[blockIdx.x] = b;
  }
}

// ---------------- Reduce partials, compute bin_width, zero hist ----------------
__global__ void __launch_bounds__(256) k_minmax_final(Ws* __restrict__ ws, int nparts) {
  __shared__ float smin[256], smax[256];
  int t = threadIdx.x;
  float vmin = FLT_MAX, vmax = -FLT_MAX;
  for (int i = t; i < nparts; i += 256) {
    vmin = fminf(vmin, ws->pmin[i]);
    vmax = fmaxf(vmax, ws->pmax[i]);
  }
  smin[t] = vmin; smax[t] = vmax;
  __syncthreads();
  for (int off = 128; off > 0; off >>= 1) {
    if (t < off) { smin[t] = fminf(smin[t], smin[t + off]); smax[t] = fmaxf(smax[t], smax[t + off]); }
    __syncthreads();
  }
  if (t == 0) {
    float mn = smin[0], mx = smax[0];
    ws->min_val = mn; ws->max_val = mx;
    float bw = (mx - mn) / (float)BINS;   // fp32, matches reference
    ws->bin_width = bw;
    ws->safe_bw = (bw == 0.0f) ? 1.0f : bw;
  }
  for (int i = t; i < BINS; i += 256) ws->hist[i] = 0u;
}

// ---------------- Pass 2: histogram (LDS-private then global flush) ----------------
__global__ void __launch_bounds__(256) k_hist(const float* __restrict__ x, long long n,
                                              Ws* __restrict__ ws) {
  __shared__ unsigned int lh[BINS];
  for (int i = threadIdx.x; i < BINS; i += 256) lh[i] = 0u;
  __syncthreads();
  float minv = ws->min_val;
  float sbw = ws->safe_bw;
  long long n4 = n >> 2;
  const float4* __restrict__ x4 = (const float4*)x;
  long long stride = (long long)gridDim.x * blockDim.x;
  for (long long i = (long long)blockIdx.x * blockDim.x + threadIdx.x; i < n4; i += stride) {
    float4 v = x4[i];
    int a = (int)floorf((v.x - minv) / sbw);
    int b = (int)floorf((v.y - minv) / sbw);
    int c = (int)floorf((v.z - minv) / sbw);
    int d = (int)floorf((v.w - minv) / sbw);
    a = min(BINS - 1, max(0, a));
    b = min(BINS - 1, max(0, b));
    c = min(BINS - 1, max(0, c));
    d = min(BINS - 1, max(0, d));
    atomicAdd(&lh[a], 1u);
    atomicAdd(&lh[b], 1u);
    atomicAdd(&lh[c], 1u);
    atomicAdd(&lh[d], 1u);
  }
  for (long long i = (n4 << 2) + (long long)blockIdx.x * blockDim.x + threadIdx.x; i < n; i += stride) {
    int a = (int)floorf((x[i] - minv) / sbw);
    a = min(BINS - 1, max(0, a));
    atomicAdd(&lh[a], 1u);
  }
  __syncthreads();
  for (int i = threadIdx.x; i < BINS; i += 256) {
    unsigned int c = lh[i];
    if (c) atomicAdd(&ws->hist[i], c);
  }
}

// ---------------- Phase 3a: cumsum + greedy-trajectory simulation ----------------
// The trajectory of (sb,eb) states is independent of the norms (every changed
// iteration before the break is accepted), so we record all candidate states
// and evaluate norms in parallel afterwards.
__global__ void __launch_bounds__(256) k_search(Ws* __restrict__ ws) {
  __shared__ float csum[BINS];
  __shared__ float part[256];
  int t = threadIdx.x;

  // convert hist -> float; per-thread chunk running sums
  float loc[8];
  float s = 0.0f;
  #pragma unroll
  for (int k = 0; k < 8; ++k) {
    float h = (float)ws->hist[t * 8 + k];
    ws->histf[t * 8 + k] = h;
    s += h;
    loc[k] = s;
  }
  part[t] = s;
  __syncthreads();
  // Hillis-Steele inclusive scan of the 256 chunk sums
  for (int off = 1; off < 256; off <<= 1) {
    float add = (t >= off) ? part[t - off] : 0.0f;
    __syncthreads();
    part[t] += add;
    __syncthreads();
  }
  float excl = (t == 0) ? 0.0f : part[t - 1];
  #pragma unroll
  for (int k = 0; k < 8; ++k) csum[t * 8 + k] = excl + loc[k];
  __syncthreads();

  if (t != 0) return;

  // --- sequential greedy trajectory (thread 0, csum in LDS, cached pointers) ---
  float total = csum[BINS - 1];
  float alpha = 0.0f, beta = 1.0f;
  int sb = 0, eb = BINS - 1;
  int nst = 0;

  float na = alpha + STEPF;
  float vna = na * total;
  int L = 0;                              // first idx with csum[idx] >= vna
  float cL = csum[0];
  while (L < BINS && cL < vna) { ++L; cL = (L < BINS) ? csum[L] : FLT_MAX; }

  int Rm = BINS - 1;                      // last idx with csum[idx] <= vnb
  float cR = csum[Rm];

  long iter = 0;
  while (alpha < beta && sb < eb && iter < 400000) {
    ++iter;
    float nb = beta - STEPF;
    float vnb = nb * total;
    while (Rm >= 0 && cR > vnb) { --Rm; cR = (Rm >= 0) ? csum[Rm] : -FLT_MAX; }
    int l = (L < sb) ? sb : ((L > eb) ? eb : L);
    int r = (Rm < sb) ? sb : ((Rm > eb) ? eb : Rm);
    if ((l - sb) > (eb - r)) {
      sb = l;
      alpha = na;
      na = alpha + STEPF;
      vna = na * total;
      while (L < BINS && cL < vna) { ++L; cL = (L < BINS) ? csum[L] : FLT_MAX; }
      if (nst < BINS) ws->states[nst] = make_int2(sb, eb);
      ++nst;
    } else {
      if (r != eb) {
        eb = r;
        if (nst < BINS) ws->states[nst] = make_int2(sb, eb);
        ++nst;
      }
      beta = nb;
    }
  }
  ws->n_states = (nst < BINS) ? nst : BINS;
}

// ---------------- Phase 3b: evaluate quantization error for all states ----------------
__global__ void __launch_bounds__(256) k_eval(Ws* __restrict__ ws) {
  int i = blockIdx.x;
  if (i >= ws->n_states) return;
  int2 st = ws->states[i];
  float bw = ws->bin_width;
  float cnt = (float)(st.y - st.x + 1);
  float w = bw * cnt / (float)DSTN;       // dst_w
  int t = threadIdx.x;
  if (w == 0.0f) {
    if (t == 0) ws->norms[i] = 0.0f;
    return;
  }
  float hw = 0.5f * w;
  float hw3 = hw * hw * hw;
  float nsb = (float)st.x;
  float sum = 0.0f;
  #pragma unroll
  for (int k = 0; k < 8; ++k) {
    int j = t + 256 * k;
    float h = ws->histf[j];
    float begin = ((float)j - nsb) * bw;
    float end = begin + bw;
    float db = fminf(fmaxf(floorf(begin / w), 0.0f), (float)(DSTN - 1));
    float de = fminf(fmaxf(floorf(end / w), 0.0f), (float)(DSTN - 1));
    float density = h / bw;
    float dbc = (db + 0.5f) * w;
    float a1 = begin - dbc;
    float n1 = density * (hw3 - a1 * a1 * a1) / 3.0f;       // _get_norm(begin-db_c, w/2)
    float nmid = density * (hw3 + hw3) / 3.0f;              // _get_norm(-w/2, w/2)
    float dec = de * w + hw;
    float a3 = end - dec;
    float n3 = density * (a3 * a3 * a3 + hw3) / 3.0f;       // _get_norm(-w/2, end-de_c)
    sum += n1 + (de - db - 1.0f) * nmid + n3;
  }
  __shared__ float red[256];
  red[t] = sum;
  __syncthreads();
  for (int off = 128; off > 0; off >>= 1) {
    if (t < off) red[t] += red[t + off];
    __syncthreads();
  }
  if (t == 0) ws->norms[i] = red[0];
}

// ---------------- Phase 3c: first norm increase -> final range ----------------
__global__ void __launch_bounds__(256) k_final(Ws* __restrict__ ws, float* __restrict__ out) {
  __shared__ int sbrk[256];
  int N = ws->n_states;
  int t = threadIdx.x;
  int loc = 0x7fffffff;
  for (int i = t + 1; i < N; i += 256) {
    if (ws->norms[i] > ws->norms[i - 1]) loc = min(loc, i);
  }
  sbrk[t] = loc;
  __syncthreads();
  for (int off = 128; off > 0; off >>= 1) {
    if (t < off) sbrk[t] = min(sbrk[t], sbrk[t + off]);
    __syncthreads();
  }
  if (t == 0) {
    int sb, eb;
    if (N == 0) { sb = 0; eb = BINS - 1; }
    else {
      int ib = sbrk[0];
      int fi = (ib != 0x7fffffff) ? (ib - 1) : (N - 1);
      int2 st = ws->states[fi];
      sb = st.x; eb = st.y;
    }
    float minv = ws->min_val, bw = ws->bin_width;
    out[0] = minv + bw * (float)sb;
    out[1] = minv + bw * (float)(eb + 1);
  }
}

extern "C" void kernel_launch(void* const* d_in, const int* in_sizes, int n_in,
                              void* d_out, int out_size, void* d_ws, size_t ws_size,
                              hipStream_t stream) {
  const float* x = (const float*)d_in[0];
  long long n = (long long)in_sizes[0];
  Ws* ws = (Ws*)d_ws;
  float* out = (float*)d_out;

  k_minmax<<<NPART, 256, 0, stream>>>(x, n, ws);
  k_minmax_final<<<1, 256, 0, stream>>>(ws, NPART);
  k_hist<<<NPART, 256, 0, stream>>>(x, n, ws);
  k_search<<<1, 256, 0, stream>>>(ws);
  k_eval<<<BINS, 256, 0, stream>>>(ws);
  k_final<<<1, 256, 0, stream>>>(ws, out);
}

// Round 2
// 1333.624 us; speedup vs baseline: 11.0161x; 11.0161x over previous
//
#include <hip/hip_runtime.h>
#include <float.h>
#include <math.h>

#define BINS 2048
#define DSTN 8
#define STEPF 1e-5f
#define NPART 1024
#define MAXST 4096

struct Ws {
  float pmin[NPART];
  float pmax[NPART];
  float min_val, max_val, bin_width, safe_bw;
  int   n_states;
  int   pad[3];
  unsigned int hist[BINS];
  float histf[BINS];
  float norms[MAXST];
  int2  states[MAXST];
};

// ---------------- Pass 1: block-partial min/max ----------------
__global__ void __launch_bounds__(256) k_minmax(const float* __restrict__ x, long long n,
                                                Ws* __restrict__ ws) {
  long long n4 = n >> 2;
  float vmin = FLT_MAX, vmax = -FLT_MAX;
  const float4* __restrict__ x4 = (const float4*)x;
  long long stride = (long long)gridDim.x * blockDim.x;
  for (long long i = (long long)blockIdx.x * blockDim.x + threadIdx.x; i < n4; i += stride) {
    float4 v = x4[i];
    vmin = fminf(vmin, fminf(fminf(v.x, v.y), fminf(v.z, v.w)));
    vmax = fmaxf(vmax, fmaxf(fmaxf(v.x, v.y), fmaxf(v.z, v.w)));
  }
  for (long long i = (n4 << 2) + (long long)blockIdx.x * blockDim.x + threadIdx.x; i < n; i += stride) {
    float v = x[i];
    vmin = fminf(vmin, v); vmax = fmaxf(vmax, v);
  }
  for (int off = 32; off > 0; off >>= 1) {
    vmin = fminf(vmin, __shfl_down(vmin, off));
    vmax = fmaxf(vmax, __shfl_down(vmax, off));
  }
  __shared__ float smin[4], smax[4];
  int wid = threadIdx.x >> 6;
  if ((threadIdx.x & 63) == 0) { smin[wid] = vmin; smax[wid] = vmax; }
  __syncthreads();
  if (threadIdx.x == 0) {
    float a = smin[0], b = smax[0];
    int nw = (int)(blockDim.x >> 6);
    for (int w = 1; w < nw; ++w) { a = fminf(a, smin[w]); b = fmaxf(b, smax[w]); }
    ws->pmin[blockIdx.x] = a; ws->pmax[blockIdx.x] = b;
  }
}

// ---------------- Reduce partials, compute bin_width, zero hist ----------------
__global__ void __launch_bounds__(256) k_minmax_final(Ws* __restrict__ ws, int nparts) {
  __shared__ float smin[256], smax[256];
  int t = threadIdx.x;
  float vmin = FLT_MAX, vmax = -FLT_MAX;
  for (int i = t; i < nparts; i += 256) {
    vmin = fminf(vmin, ws->pmin[i]);
    vmax = fmaxf(vmax, ws->pmax[i]);
  }
  smin[t] = vmin; smax[t] = vmax;
  __syncthreads();
  for (int off = 128; off > 0; off >>= 1) {
    if (t < off) { smin[t] = fminf(smin[t], smin[t + off]); smax[t] = fmaxf(smax[t], smax[t + off]); }
    __syncthreads();
  }
  if (t == 0) {
    float mn = smin[0], mx = smax[0];
    ws->min_val = mn; ws->max_val = mx;
    float bw = (mx - mn) / (float)BINS;
    ws->bin_width = bw;
    ws->safe_bw = (bw == 0.0f) ? 1.0f : bw;
  }
  for (int i = t; i < BINS; i += 256) ws->hist[i] = 0u;
}

// ---------------- Pass 2: histogram (LDS-private then global flush) ----------------
__global__ void __launch_bounds__(256) k_hist(const float* __restrict__ x, long long n,
                                              Ws* __restrict__ ws) {
  __shared__ unsigned int lh[BINS];
  for (int i = threadIdx.x; i < BINS; i += 256) lh[i] = 0u;
  __syncthreads();
  float minv = ws->min_val;
  float sbw = ws->safe_bw;
  long long n4 = n >> 2;
  const float4* __restrict__ x4 = (const float4*)x;
  long long stride = (long long)gridDim.x * blockDim.x;
  for (long long i = (long long)blockIdx.x * blockDim.x + threadIdx.x; i < n4; i += stride) {
    float4 v = x4[i];
    int a = (int)floorf((v.x - minv) / sbw);
    int b = (int)floorf((v.y - minv) / sbw);
    int c = (int)floorf((v.z - minv) / sbw);
    int d = (int)floorf((v.w - minv) / sbw);
    a = min(BINS - 1, max(0, a));
    b = min(BINS - 1, max(0, b));
    c = min(BINS - 1, max(0, c));
    d = min(BINS - 1, max(0, d));
    atomicAdd(&lh[a], 1u);
    atomicAdd(&lh[b], 1u);
    atomicAdd(&lh[c], 1u);
    atomicAdd(&lh[d], 1u);
  }
  for (long long i = (n4 << 2) + (long long)blockIdx.x * blockDim.x + threadIdx.x; i < n; i += stride) {
    int a = (int)floorf((x[i] - minv) / sbw);
    a = min(BINS - 1, max(0, a));
    atomicAdd(&lh[a], 1u);
  }
  __syncthreads();
  for (int i = threadIdx.x; i < BINS; i += 256) {
    unsigned int c = lh[i];
    if (c) atomicAdd(&ws->hist[i], c);
  }
}

// ---------------- Phase 3a: cumsum + event-driven greedy trajectory ----------------
// The (sb,eb) trajectory is independent of the norms (every changed iteration
// before the break is accepted). We enumerate all candidate states, evaluating
// norms in parallel afterwards. The reference loop's no-change iterations
// (beta -= STEP with no searchsorted crossing) are batch-jumped using the fact
// that fp32 repeated subtraction of a constant is exactly arithmetic within a
// binade (no round-to-even ties for S=1e-5f with beta in [0.25,1]); crossing
// indices are verified against the actual fp32 comparisons, so the state
// sequence is bit-identical to the step-by-step loop.
__global__ void __launch_bounds__(256) k_search(Ws* __restrict__ ws) {
  __shared__ float csum[BINS];
  __shared__ float part[256];
  int t = threadIdx.x;

  float loc[8];
  float s = 0.0f;
  #pragma unroll
  for (int k = 0; k < 8; ++k) {
    float h = (float)ws->hist[t * 8 + k];
    ws->histf[t * 8 + k] = h;
    s += h;
    loc[k] = s;
  }
  part[t] = s;
  __syncthreads();
  for (int off = 1; off < 256; off <<= 1) {
    float add = (t >= off) ? part[t - off] : 0.0f;
    __syncthreads();
    part[t] += add;
    __syncthreads();
  }
  float excl = (t == 0) ? 0.0f : part[t - 1];
  #pragma unroll
  for (int k = 0; k < 8; ++k) csum[t * 8 + k] = excl + loc[k];
  __syncthreads();

  if (t != 0) return;

  const float S = STEPF;
  float T = csum[BINS - 1];
  float alpha = 0.0f, beta = 1.0f;
  int sb = 0, eb = BINS - 1;
  int nst = 0;

  float na = S;                  // fl(0 + S)
  float vna = na * T;
  int lI = 0; float cL = csum[0];
  while (lI < BINS && cL < vna) { ++lI; cL = (lI < BINS) ? csum[lI] : FLT_MAX; }

  int Rm = BINS - 1; float cR = csum[Rm];
  float C = cR;                  // csum[eb]

  int trips = 0;
  while (alpha < beta && sb < eb && trips < 200000) {
    ++trips;
    float nb = beta - S;
    float vnb = nb * T;
    while (Rm >= 0 && cR > vnb) { --Rm; cR = (Rm >= 0) ? csum[Rm] : -FLT_MAX; }
    int l = lI < sb ? sb : (lI > eb ? eb : lI);
    int r = Rm < sb ? sb : (Rm > eb ? eb : Rm);
    int pl = l - sb, pr = eb - r;
    if (pl > pr) {
      // left take: one exact fp32 alpha step, state changes
      sb = l;
      alpha = na; na = alpha + S; vna = na * T;
      while (lI < BINS && cL < vna) { ++lI; cL = (lI < BINS) ? csum[lI] : FLT_MAX; }
      if (nst < MAXST) ws->states[nst] = make_int2(sb, eb);
      ++nst;
      continue;
    }
    beta = nb;
    if (pr > 0) {
      // right event: state changes
      eb = r;
      C = (r == Rm) ? cR : csum[r];
      if (nst < MAXST) ws->states[nst] = make_int2(sb, eb);
      ++nst;
      continue;
    }
    // no-change right step executed (beta = nb). Batch-jump the rest of the run.
    if (!(alpha < beta)) break;
    float bn2 = beta - S;
    float d = beta - bn2;                       // exact (Sterbenz)
    if (!(d > 0.0f)) break;                     // paranoia
    unsigned bb = __float_as_uint(beta);
    float binlo = __uint_as_float(bb & 0xff800000u);
    if ((bb & 0x007fffffu) == 0u) binlo *= 0.5f;
    double dd = (double)d;
    double db0 = (double)beta;
    long long jmax = (long long)floor((db0 - (double)binlo) / dd);
    if (jmax < 1) continue;
    // ja: smallest j>=1 with fl((beta - j*d)*T) < C   (monotone in j)
    long long ja = (long long)floor((db0 - (double)C / (double)T) / dd) + 1;
    if (ja < 1) ja = 1;
    if (ja > jmax + 1) ja = jmax + 1;
    while (ja > 1) {
      float nbj = (float)(db0 - (double)(ja - 1) * dd);
      if (nbj * T < C) --ja; else break;
    }
    while (ja <= jmax) {
      float nbj = (float)(db0 - (double)ja * dd);
      if (nbj * T < C) break; else ++ja;
    }
    long long j;
    double gap = db0 - (double)alpha;
    if (gap < dd * (double)(ja + 2)) {
      // loop termination (beta <= alpha) may come first
      long long jb = (long long)floor(gap / dd);
      if (jb < 1) jb = 1;
      while (jb > 1) {
        float nbj = (float)(db0 - (double)(jb - 1) * dd);
        if (nbj <= alpha) --jb; else break;
      }
      while (jb <= jmax) {
        float nbj = (float)(db0 - (double)jb * dd);
        if (nbj <= alpha) break; else ++jb;
      }
      j = (jb < ja) ? jb : (ja - 1);
    } else {
      j = ja - 1;
    }
    if (j > jmax) j = jmax;
    if (j >= 1) beta = (float)(db0 - (double)j * dd);
  }
  ws->n_states = (nst < MAXST) ? nst : MAXST;
}

// ---------------- Phase 3b: evaluate quantization error for all states ----------------
__global__ void __launch_bounds__(256) k_eval(Ws* __restrict__ ws) {
  int i = blockIdx.x;
  if (i >= ws->n_states) return;
  int2 st = ws->states[i];
  float bw = ws->bin_width;
  float cnt = (float)(st.y - st.x + 1);
  float w = bw * cnt / (float)DSTN;
  int t = threadIdx.x;
  if (w == 0.0f) {
    if (t == 0) ws->norms[i] = 0.0f;
    return;
  }
  float hw = 0.5f * w;
  float hw3 = hw * hw * hw;
  float nsb = (float)st.x;
  float sum = 0.0f;
  #pragma unroll
  for (int k = 0; k < 8; ++k) {
    int j = t + 256 * k;
    float h = ws->histf[j];
    float begin = ((float)j - nsb) * bw;
    float end = begin + bw;
    float db = fminf(fmaxf(floorf(begin / w), 0.0f), (float)(DSTN - 1));
    float de = fminf(fmaxf(floorf(end / w), 0.0f), (float)(DSTN - 1));
    float density = h / bw;
    float dbc = (db + 0.5f) * w;
    float a1 = begin - dbc;
    float n1 = density * (hw3 - a1 * a1 * a1) / 3.0f;
    float nmid = density * (hw3 + hw3) / 3.0f;
    float dec = de * w + hw;
    float a3 = end - dec;
    float n3 = density * (a3 * a3 * a3 + hw3) / 3.0f;
    sum += n1 + (de - db - 1.0f) * nmid + n3;
  }
  __shared__ float red[256];
  red[t] = sum;
  __syncthreads();
  for (int off = 128; off > 0; off >>= 1) {
    if (t < off) red[t] += red[t + off];
    __syncthreads();
  }
  if (t == 0) ws->norms[i] = red[0];
}

// ---------------- Phase 3c: first norm increase -> final range ----------------
__global__ void __launch_bounds__(256) k_final(Ws* __restrict__ ws, float* __restrict__ out) {
  __shared__ int sbrk[256];
  int N = ws->n_states;
  int t = threadIdx.x;
  int loc = 0x7fffffff;
  for (int i = t + 1; i < N; i += 256) {
    if (ws->norms[i] > ws->norms[i - 1]) loc = min(loc, i);
  }
  sbrk[t] = loc;
  __syncthreads();
  for (int off = 128; off > 0; off >>= 1) {
    if (t < off) sbrk[t] = min(sbrk[t], sbrk[t + off]);
    __syncthreads();
  }
  if (t == 0) {
    int sb, eb;
    int N2 = N;
    if (N2 == 0) { sb = 0; eb = BINS - 1; }
    else {
      int ib = sbrk[0];
      int fi = (ib != 0x7fffffff) ? (ib - 1) : (N2 - 1);
      int2 st = ws->states[fi];
      sb = st.x; eb = st.y;
    }
    float minv = ws->min_val, bw = ws->bin_width;
    out[0] = minv + bw * (float)sb;
    out[1] = minv + bw * (float)(eb + 1);
  }
}

extern "C" void kernel_launch(void* const* d_in, const int* in_sizes, int n_in,
                              void* d_out, int out_size, void* d_ws, size_t ws_size,
                              hipStream_t stream) {
  const float* x = (const float*)d_in[0];
  long long n = (long long)in_sizes[0];
  Ws* ws = (Ws*)d_ws;
  float* out = (float*)d_out;

  k_minmax<<<NPART, 256, 0, stream>>>(x, n, ws);
  k_minmax_final<<<1, 256, 0, stream>>>(ws, NPART);
  k_hist<<<NPART, 256, 0, stream>>>(x, n, ws);
  k_search<<<1, 256, 0, stream>>>(ws);
  k_eval<<<MAXST, 256, 0, stream>>>(ws);
  k_final<<<1, 256, 0, stream>>>(ws, out);
}